// Round 6
// baseline (205.657 us; speedup 1.0000x reference)
//
#include <hip/hip_runtime.h>
#include <hip/hip_fp16.h>

#define DIM 64
#define BIN_SHIFT 7
#define BINSZ 128      // nodes per bin
#define MAXBINS 1024   // supports N up to 131072
#define PB 512         // edge-slice blocks for hist/bucket (power of 2)
#define PB_LOG 9

typedef __attribute__((ext_vector_type(2))) float floatx2;
typedef __attribute__((ext_vector_type(4))) float f32x4;
typedef __attribute__((ext_vector_type(8))) _Float16 f16x8;
typedef __attribute__((ext_vector_type(4))) _Float16 f16x4;

// ---------------- pass 1: per-block LDS histogram -> C[blk][bin] ----------------

__global__ __launch_bounds__(256) void k_hist(const int* __restrict__ dst,
                                              int* __restrict__ C, int E, int NB) {
    __shared__ int h[MAXBINS];
    for (int i = threadIdx.x; i < NB; i += 256) h[i] = 0;
    __syncthreads();
    int per = (E + PB - 1) / PB;
    int e0 = blockIdx.x * per;
    int e1 = e0 + per; if (e1 > E) e1 = E;
    for (int e = e0 + (int)threadIdx.x; e < e1; e += 256)
        atomicAdd(&h[dst[e] >> BIN_SHIFT], 1);
    __syncthreads();
    for (int i = threadIdx.x; i < NB; i += 256)
        C[blockIdx.x * NB + i] = h[i];
}

// ---------------- pass 2a: chunk-local exclusive scan of C (bin-major order) ----------------

__global__ __launch_bounds__(1024) void k_scanA(const int* __restrict__ C,
                                                int* __restrict__ S,
                                                int* __restrict__ bsums, int NB, int M) {
    __shared__ int sh[1024];
    int tid = threadIdx.x;
    int j0 = blockIdx.x * 4096 + tid * 4;
    int v[4]; int sum = 0;
#pragma unroll
    for (int t = 0; t < 4; ++t) {
        int j = j0 + t; int x = 0;
        if (j < M) { int bin = j >> PB_LOG, blk = j & (PB - 1); x = C[blk * NB + bin]; }
        v[t] = sum; sum += x;
    }
    sh[tid] = sum;
    __syncthreads();
#pragma unroll
    for (int d = 1; d < 1024; d <<= 1) {
        int t = (tid >= d) ? sh[tid - d] : 0;
        __syncthreads();
        sh[tid] += t;
        __syncthreads();
    }
    int excl = sh[tid] - sum;
#pragma unroll
    for (int t = 0; t < 4; ++t) {
        int j = j0 + t;
        if (j < M) S[j] = excl + v[t];
    }
    if (tid == 1023) bsums[blockIdx.x] = sh[1023];
}

// ---------------- pass 2b: exclusive scan of chunk sums ----------------

__global__ __launch_bounds__(1024) void k_scanB(int* __restrict__ bsums, int nb) {
    __shared__ int s[1024];
    int tid = threadIdx.x;
    int v = (tid < nb) ? bsums[tid] : 0;
    s[tid] = v;
    __syncthreads();
#pragma unroll
    for (int d = 1; d < 1024; d <<= 1) {
        int t = (tid >= d) ? s[tid - d] : 0;
        __syncthreads();
        s[tid] += t;
        __syncthreads();
    }
    if (tid < nb) bsums[tid] = s[tid] - v;
}

// ---------------- pass 3: one-pass bucket scatter, LDS cursors ----------------

__global__ __launch_bounds__(256) void k_bucket(const int* __restrict__ src,
                                                const int* __restrict__ dst,
                                                const int* __restrict__ S,
                                                const int* __restrict__ bsums,
                                                int* __restrict__ bkt, int E, int NB) {
    __shared__ int lcur[MAXBINS];
    int blk = blockIdx.x;
    for (int i = threadIdx.x; i < NB; i += 256) {
        int j = i * PB + blk;
        lcur[i] = S[j] + bsums[j >> 12];
    }
    __syncthreads();
    int per = (E + PB - 1) / PB;
    int e0 = blk * per;
    int e1 = e0 + per; if (e1 > E) e1 = E;
    for (int e = e0 + (int)threadIdx.x; e < e1; e += 256) {
        int d = dst[e];
        int pos = atomicAdd(&lcur[d >> BIN_SHIFT], 1);
        bkt[pos] = src[e] | ((d & (BINSZ - 1)) << 24);
    }
}

// ---------------- pass 4: per-bin counting sort -> csr, off, dinv; + gbound; + zero out ----------------

__global__ __launch_bounds__(256) void k_binsort(const int* __restrict__ bkt,
                                                 const int* __restrict__ S,
                                                 const int* __restrict__ bsums,
                                                 int* __restrict__ csr,
                                                 int* __restrict__ off,
                                                 float* __restrict__ dinv,
                                                 const int* __restrict__ batch,
                                                 int* __restrict__ goff,
                                                 float* __restrict__ outz,
                                                 int N, int G, int E, int NB) {
    __shared__ int cnt[BINSZ], bas[BINSZ], cur[BINSZ];
    __shared__ int wsum[4];
    int tid = threadIdx.x;
    int b = blockIdx.x;
    // zero the pooled output (k_gather_pool accumulates via atomics)
    for (int i = b * 256 + tid; i < G * DIM; i += NB * 256) outz[i] = 0.f;
    int j0 = b << PB_LOG;
    int s0 = S[j0] + bsums[j0 >> 12];
    int s1 = E;
    if (b + 1 < NB) { int j1 = (b + 1) << PB_LOG; s1 = S[j1] + bsums[j1 >> 12]; }
    if (tid < BINSZ) { cnt[tid] = 0; cur[tid] = 0; }
    __syncthreads();
    for (int i = s0 + tid; i < s1; i += 256)
        atomicAdd(&cnt[(bkt[i] >> 24) & (BINSZ - 1)], 1);
    __syncthreads();
    int my = (tid < BINSZ) ? cnt[tid] : 0;
    int lane = tid & 63, wv = tid >> 6;
    int x = my;
#pragma unroll
    for (int d = 1; d < 64; d <<= 1) {
        int t = __shfl_up(x, d);
        if (lane >= d) x += t;
    }
    if (lane == 63) wsum[wv] = x;
    __syncthreads();
    int prefix = 0;
    for (int w = 0; w < wv; ++w) prefix += wsum[w];
    int ex = x + prefix - my;               // exclusive base
    if (tid < BINSZ) {
        bas[tid] = ex;
        int v = (b << BIN_SHIFT) + tid;
        if (v < N) {
            off[v] = s0 + ex;
            dinv[v] = rsqrtf((float)(my + 1));   // +1 self-loop
            if (v == N - 1) off[N] = E;
            // fused gbound (batch sorted)
            int bb = batch[v];
            int prev = (v == 0) ? -1 : batch[v - 1];
            for (int g = prev + 1; g <= bb; ++g) goff[g] = v;
            if (v == N - 1)
                for (int g = bb + 1; g <= G; ++g) goff[g] = N;
        }
    }
    __syncthreads();
    for (int i = s0 + tid; i < s1; i += 256) {
        int p = bkt[i];
        int lo = (p >> 24) & (BINSZ - 1);
        int li = atomicAdd(&cur[lo], 1);
        csr[s0 + bas[lo] + li] = p & 0xFFFFFF;
    }
}

// ---------------- skinny GEMM via MFMA: hs[row] = (X[row] @ W) * dinv[row] ----------------
// fp8 out, SPLIT into two half-tables (cols 0-31 -> YA, 32-63 -> YB), 32 B rows each,
// so each gather half touches a 3.2 MB footprint (per-XCD L2-resident).
// k-map bijection: k = 32s + 8*(lane>>4) + elem, applied to BOTH A and B fragments.
// D layout (HW-verified): col = lane&15, row = 4*(lane>>4) + reg.

__global__ __launch_bounds__(256) void k_gemm(const float* __restrict__ X,
                                              const float* __restrict__ W,
                                              const float* __restrict__ dinv,
                                              unsigned int* __restrict__ YA,
                                              unsigned int* __restrict__ YB, int N) {
    __shared__ float Os[16 * 68];
    int tid = threadIdx.x;
    int lane = tid & 63, w = tid >> 6;
    int m = lane & 15, g = lane >> 4;
    int row0 = blockIdx.x * 16;
    int row = row0 + m;

    f16x8 B0, B1;
    {
        int n = (w << 4) + m;
        const float* wp = W + (g << 3) * 64 + n;
#pragma unroll
        for (int j = 0; j < 8; ++j) B0[j] = (_Float16)wp[j * 64];
        wp += 32 * 64;
#pragma unroll
        for (int j = 0; j < 8; ++j) B1[j] = (_Float16)wp[j * 64];
    }
    f16x8 A0, A1;
    {
        float4 u0 = make_float4(0.f, 0.f, 0.f, 0.f), u1 = u0, u2 = u0, u3 = u0;
        if (row < N) {
            const float* xp = X + (size_t)row * DIM + (g << 3);
            u0 = *(const float4*)(xp);
            u1 = *(const float4*)(xp + 4);
            u2 = *(const float4*)(xp + 32);
            u3 = *(const float4*)(xp + 36);
        }
        A0[0] = (_Float16)u0.x; A0[1] = (_Float16)u0.y; A0[2] = (_Float16)u0.z; A0[3] = (_Float16)u0.w;
        A0[4] = (_Float16)u1.x; A0[5] = (_Float16)u1.y; A0[6] = (_Float16)u1.z; A0[7] = (_Float16)u1.w;
        A1[0] = (_Float16)u2.x; A1[1] = (_Float16)u2.y; A1[2] = (_Float16)u2.z; A1[3] = (_Float16)u2.w;
        A1[4] = (_Float16)u3.x; A1[5] = (_Float16)u3.y; A1[6] = (_Float16)u3.z; A1[7] = (_Float16)u3.w;
    }
    f32x4 acc = {0.f, 0.f, 0.f, 0.f};
    acc = __builtin_amdgcn_mfma_f32_16x16x32_f16(A0, B0, acc, 0, 0, 0);
    acc = __builtin_amdgcn_mfma_f32_16x16x32_f16(A1, B1, acc, 0, 0, 0);
#pragma unroll
    for (int j = 0; j < 4; ++j)
        Os[((g << 2) + j) * 68 + (w << 4) + m] = acc[j];
    __syncthreads();

    int r = tid >> 4, c = tid & 15;
    int orow = row0 + r;
    unsigned int* T = (c < 8) ? YA : YB;
    int ci = c & 7;
    if (orow < N) {
        float4 o = *(const float4*)(Os + r * 68 + (c << 2));
        float s = dinv[orow];
        int p = 0;
        p = __builtin_amdgcn_cvt_pk_fp8_f32(o.x * s, o.y * s, p, false);
        p = __builtin_amdgcn_cvt_pk_fp8_f32(o.z * s, o.w * s, p, true);
        T[(size_t)orow * 8 + ci] = (unsigned int)p;
    } else if (orow == N) {
        T[(size_t)orow * 8 + ci] = 0u;   // +0 in e4m3 (gather pad row)
    }
}

// ---------------- gather core: 8-lane group per node, ONE half-table (32 B rows) ----------------
// lane l3 owns cols 4*l3..4*l3+3 of the half. 8 edges / 8 loads in flight per chunk.
// Padding slots read row N (zeros). Next chunk's csr word prefetched under conversions.

__device__ __forceinline__ float4 gather_rows8(const unsigned int* __restrict__ tab,
                                               const int* __restrict__ csr,
                                               int k0, int k1, int v, int l3, int gbase,
                                               int N) {
    float4 a, b;
    {
        unsigned int u = tab[((unsigned)v << 3) | l3];     // self-loop term
        floatx2 f0 = __builtin_amdgcn_cvt_pk_f32_fp8((int)u, false);
        floatx2 f1 = __builtin_amdgcn_cvt_pk_f32_fp8((int)u, true);
        a = make_float4(f0.x, f0.y, f1.x, f1.y);
        b = make_float4(0.f, 0.f, 0.f, 0.f);
    }
    int kb = k0;
    int idx = (k0 + l3 < k1) ? csr[k0 + l3] : N;
    while (kb < k1) {
        int nkb = kb + 8;
        unsigned int uu[8];
#pragma unroll
        for (int t = 0; t < 8; ++t) {
            int e = __shfl(idx, gbase + t);
            uu[t] = tab[((unsigned)e << 3) | l3];
        }
        idx = (nkb + l3 < k1) ? csr[nkb + l3] : N;   // prefetch next chunk
#pragma unroll
        for (int t = 0; t < 8; t += 2) {
            floatx2 f0 = __builtin_amdgcn_cvt_pk_f32_fp8((int)uu[t], false);
            floatx2 f1 = __builtin_amdgcn_cvt_pk_f32_fp8((int)uu[t], true);
            floatx2 g0 = __builtin_amdgcn_cvt_pk_f32_fp8((int)uu[t + 1], false);
            floatx2 g1 = __builtin_amdgcn_cvt_pk_f32_fp8((int)uu[t + 1], true);
            a.x += f0.x; a.y += f0.y; a.z += f1.x; a.w += f1.y;
            b.x += g0.x; b.y += g0.y; b.z += g1.x; b.w += g1.y;
        }
        kb = nkb;
    }
    return make_float4(a.x + b.x, a.y + b.y, a.z + b.z, a.w + b.w);
}

// ---------------- layer-1 gather, XCD-partitioned halves -> raw fp16 sums in agg ----------------
// xcd = blockIdx&7 (HW round-robin): xcd 0-3 -> half A, 4-7 -> half B. Each XCD's random
// stream touches only its 3.2 MB half-table -> L2-resident. 32 nodes/block, 8 lanes/node.

__global__ __launch_bounds__(256) void k_gather_half(const unsigned int* __restrict__ hsA,
                                                     const unsigned int* __restrict__ hsB,
                                                     const int* __restrict__ csr,
                                                     const int* __restrict__ off,
                                                     __half* __restrict__ agg, int N,
                                                     int NBLK32) {
    int bb = blockIdx.x;
    int xcd = bb & 7, half = xcd >> 2, l4 = xcd & 3;
    int nb = (bb >> 3) * 4 + l4;
    if (nb >= NBLK32) return;
    int tid = threadIdx.x;
    int r = tid >> 3, l3 = tid & 7;
    int gbase = (tid & 63) & ~7;
    int v = nb * 32 + r;
    if (v >= N) return;
    const unsigned int* tab = half ? hsB : hsA;
    float4 acc = gather_rows8(tab, csr, off[v], off[v + 1], v, l3, gbase, N);
    __half2 p0 = __floats2half2_rn(acc.x, acc.y);
    __half2 p1 = __floats2half2_rn(acc.z, acc.w);
    uint2 u;
    u.x = *(unsigned int*)&p0;
    u.y = *(unsigned int*)&p1;
    ((uint2*)agg)[(size_t)v * 16 + half * 8 + l3] = u;   // cols 32*half + 4*l3 ..
}

// ---------------- layer-2 GEMM via MFMA: hs2 = (relu(agg*dinv + b1) @ W2) * dinv, fp8 halves ----------------

__global__ __launch_bounds__(256) void k_gemm2(const __half* __restrict__ agg,
                                               const float* __restrict__ W,
                                               const float* __restrict__ b1,
                                               const float* __restrict__ dinv,
                                               unsigned int* __restrict__ YA,
                                               unsigned int* __restrict__ YB, int N) {
    __shared__ float Os[16 * 68];
    int tid = threadIdx.x;
    int lane = tid & 63, w = tid >> 6;
    int m = lane & 15, g = lane >> 4;
    int row0 = blockIdx.x * 16;
    int row = row0 + m;

    f16x8 B0, B1;
    {
        int n = (w << 4) + m;
        const float* wp = W + (g << 3) * 64 + n;
#pragma unroll
        for (int j = 0; j < 8; ++j) B0[j] = (_Float16)wp[j * 64];
        wp += 32 * 64;
#pragma unroll
        for (int j = 0; j < 8; ++j) B1[j] = (_Float16)wp[j * 64];
    }
    f16x8 A0, A1;
    if (row < N) {
        float dv = dinv[row];
        const __half2* ap2 = (const __half2*)(agg + (size_t)row * 64 + (g << 3));
#pragma unroll
        for (int j = 0; j < 4; ++j) {
            float2 f = __half22float2(ap2[j]);
            float2 fb = __half22float2(ap2[j + 16]);      // +32 cols
            int k0 = (g << 3) + 2 * j;
            A0[2 * j]     = (_Float16)fmaxf(f.x * dv + b1[k0], 0.f);
            A0[2 * j + 1] = (_Float16)fmaxf(f.y * dv + b1[k0 + 1], 0.f);
            A1[2 * j]     = (_Float16)fmaxf(fb.x * dv + b1[32 + k0], 0.f);
            A1[2 * j + 1] = (_Float16)fmaxf(fb.y * dv + b1[32 + k0 + 1], 0.f);
        }
    } else {
#pragma unroll
        for (int j = 0; j < 8; ++j) { A0[j] = (_Float16)0.f; A1[j] = (_Float16)0.f; }
    }
    f32x4 acc = {0.f, 0.f, 0.f, 0.f};
    acc = __builtin_amdgcn_mfma_f32_16x16x32_f16(A0, B0, acc, 0, 0, 0);
    acc = __builtin_amdgcn_mfma_f32_16x16x32_f16(A1, B1, acc, 0, 0, 0);
#pragma unroll
    for (int j = 0; j < 4; ++j)
        Os[((g << 2) + j) * 68 + (w << 4) + m] = acc[j];
    __syncthreads();

    int r = tid >> 4, c = tid & 15;
    int orow = row0 + r;
    unsigned int* T = (c < 8) ? YA : YB;
    int ci = c & 7;
    if (orow < N) {
        float4 o = *(const float4*)(Os + r * 68 + (c << 2));
        float s = dinv[orow];
        int p = 0;
        p = __builtin_amdgcn_cvt_pk_fp8_f32(o.x * s, o.y * s, p, false);
        p = __builtin_amdgcn_cvt_pk_fp8_f32(o.z * s, o.w * s, p, true);
        T[(size_t)orow * 8 + ci] = (unsigned int)p;
    } else if (orow == N) {
        T[(size_t)orow * 8 + ci] = 0u;
    }
}

// ---------------- layer-2 gather + mean-pool, XCD-partitioned halves, atomics into out ----------------

__global__ __launch_bounds__(256) void k_gather_pool(const unsigned int* __restrict__ hsA,
                                                     const unsigned int* __restrict__ hsB,
                                                     const int* __restrict__ csr,
                                                     const int* __restrict__ off,
                                                     const float* __restrict__ dinv,
                                                     const float* __restrict__ bias,
                                                     const int* __restrict__ batch,
                                                     const int* __restrict__ goff,
                                                     float* __restrict__ out, int N,
                                                     int NBLK32) {
    __shared__ float vals[32][36];
    __shared__ int gid[32];
    int bb = blockIdx.x;
    int xcd = bb & 7, half = xcd >> 2, l4 = xcd & 3;
    int nb = (bb >> 3) * 4 + l4;
    if (nb >= NBLK32) return;                 // block-uniform, safe before barrier
    int tid = threadIdx.x;
    int r = tid >> 3, l3 = tid & 7;
    int gbase = (tid & 63) & ~7;
    int v = nb * 32 + r;

    float4 val = make_float4(0.f, 0.f, 0.f, 0.f);
    int g = -1;
    if (v < N) {
        g = batch[v];
        float dv = dinv[v];
        const unsigned int* tab = half ? hsB : hsA;
        float4 bv = ((const float4*)bias)[half * 8 + l3];
        float4 acc = gather_rows8(tab, csr, off[v], off[v + 1], v, l3, gbase, N);
        float inv = 1.0f / (float)(goff[g + 1] - goff[g]);
        val.x = fmaxf(acc.x * dv + bv.x, 0.f) * inv;
        val.y = fmaxf(acc.y * dv + bv.y, 0.f) * inv;
        val.z = fmaxf(acc.z * dv + bv.z, 0.f) * inv;
        val.w = fmaxf(acc.w * dv + bv.w, 0.f) * inv;
    }
    *(float4*)(&vals[r][l3 << 2]) = val;
    if (l3 == 0) gid[r] = g;
    __syncthreads();

    if (v < N) {
        bool leader = (r == 0) || (gid[r - 1] != g);
        if (leader) {
            float4 sacc = val;
            for (int rr = r + 1; rr < 32 && gid[rr] == g; ++rr) {
                float4 t = *(const float4*)(&vals[rr][l3 << 2]);
                sacc.x += t.x; sacc.y += t.y; sacc.z += t.z; sacc.w += t.w;
            }
            float* op = out + (size_t)g * DIM + half * 32 + (l3 << 2);
            atomicAdd(op + 0, sacc.x);
            atomicAdd(op + 1, sacc.y);
            atomicAdd(op + 2, sacc.z);
            atomicAdd(op + 3, sacc.w);
        }
    }
}

// ---------------- launch ----------------

static inline int cdiv(int a, int b) { return (a + b - 1) / b; }

extern "C" void kernel_launch(void* const* d_in, const int* in_sizes, int n_in,
                              void* d_out, int out_size, void* d_ws, size_t ws_size,
                              hipStream_t stream) {
    const float* x   = (const float*)d_in[0];
    const float* W1  = (const float*)d_in[1];
    const float* b1  = (const float*)d_in[2];
    const float* W2  = (const float*)d_in[3];
    const float* b2  = (const float*)d_in[4];
    const int*   ei  = (const int*)d_in[5];
    const int*   bat = (const int*)d_in[6];

    const int N = in_sizes[0] / DIM;
    const int E = in_sizes[5] / 2;
    const int G = out_size / DIM;
    const int NB = cdiv(N, BINSZ);           // <= MAXBINS
    const int M  = NB * PB;                  // scan length
    const int* src = ei;
    const int* dst = ei + E;
    float* out = (float*)d_out;

    // workspace: hs1A | hs1B | hs2A | hs2B | agg1 | dinv | off | goff | C | S | bsums | csr
    // bkt aliases agg1 (dead before k_gather_half writes agg1).
    unsigned int* hs1A = (unsigned int*)d_ws;                 // (N+1)*8 u
    unsigned int* hs1B = hs1A + (size_t)(N + 1) * 8;          // (N+1)*8 u
    unsigned int* hs2A = hs1B + (size_t)(N + 1) * 8;          // (N+1)*8 u
    unsigned int* hs2B = hs2A + (size_t)(N + 1) * 8;          // (N+1)*8 u
    __half* agg1   = (__half*)(hs2B + (size_t)(N + 1) * 8);   // N*64 h
    float*  dinv   = (float*)(agg1 + (size_t)N * DIM);        // N f
    int*    off    = (int*)(dinv + N);                        // N+1 i
    int*    goff   = off + (N + 1);                           // G+1 i
    int*    C      = goff + (G + 1);                          // PB*NB i
    int*    S      = C + (size_t)PB * NB;                     // PB*NB i
    int*    bsums  = S + (size_t)PB * NB;                     // up to 1024 i
    int*    csr    = bsums + 1024;                            // E i
    int*    bkt    = (int*)agg1;                              // E i (aliased)

    k_hist<<<PB, 256, 0, stream>>>(dst, C, E, NB);
    int nb2 = cdiv(M, 4096);
    k_scanA<<<nb2, 1024, 0, stream>>>(C, S, bsums, NB, M);
    k_scanB<<<1, 1024, 0, stream>>>(bsums, nb2);
    k_bucket<<<PB, 256, 0, stream>>>(src, dst, S, bsums, bkt, E, NB);
    k_binsort<<<NB, 256, 0, stream>>>(bkt, S, bsums, csr, off, dinv, bat, goff,
                                      out, N, G, E, NB);

    const int NBLK32 = cdiv(N, 32);
    const int GGRID  = 8 * cdiv(NBLK32, 4);

    // layer 1 transform: hs1{A,B} = (x @ W1) * dinv (fp8 half-tables), MFMA
    k_gemm<<<cdiv(N + 1, 16), 256, 0, stream>>>(x, W1, dinv, hs1A, hs1B, N);

    // layer 1 aggregate: agg1 = raw gather sums (fp16), XCD-partitioned halves
    k_gather_half<<<GGRID, 256, 0, stream>>>(hs1A, hs1B, csr, off, agg1, N, NBLK32);

    // layer 2 transform: hs2{A,B} = (relu(agg1*dinv + b1) @ W2) * dinv (fp8), MFMA
    k_gemm2<<<cdiv(N + 1, 16), 256, 0, stream>>>(agg1, W2, b1, dinv, hs2A, hs2B, N);

    // layer 2 gather + bias + relu + mean-pool (atomics into out), XCD-partitioned
    k_gather_pool<<<GGRID, 256, 0, stream>>>(hs2A, hs2B, csr, off, dinv, b2, bat,
                                             goff, out, N, NBLK32);
}